// Round 2
// baseline (140.975 us; speedup 1.0000x reference)
//
#include <hip/hip_runtime.h>

#define NT 4096
#define NPP 100
#define NROWS 2048
#define BLK 256
#define EPT 16           // 256*16 = 4096
#define NM 98            // interior spline unknowns
#define DTIME 0.001f

__device__ __forceinline__ float pgrid(int k) {
  return (float)((double)k * (1.0 / 99.0));
}

// One block per row. Phase A: obs -> CDF (register-resident, per-thread
// interval ownership) -> Q[100] -> PCR tridiag solve -> spline coeffs.
// Phase B: f -> CDF per element -> spline eval -> weighted accumulation.
__global__ __launch_bounds__(BLK) void wass_row_kernel(
    const float* __restrict__ f, const float* __restrict__ obs,
    float* __restrict__ rowOut) {
  const int row  = blockIdx.x;
  const int tid  = threadIdx.x;
  const int lane = tid & 63;
  const int wid  = tid >> 6;

  __shared__ float sQ[NPP];
  __shared__ float sM[NPP];
  __shared__ float4 sCo[NPP - 1];
  __shared__ float sPa[2][NM], sPb[2][NM], sPc[2][NM], sPd[2][NM];
  __shared__ float sFlast[BLK];
  __shared__ float sWo[4], sWf[4], sWoOff[4], sWfOff[4];
  __shared__ float sTotO, sTotF, sY0o, sYlo, sY0f, sYlf;

  // ---- issue BOTH rows' loads up front (overlap HBM latency) ----
  float yo[EPT], yf[EPT];
  {
    const float4* op = (const float4*)(obs + (size_t)row * NT);
    const float4* fp = (const float4*)(f + (size_t)row * NT);
    float4 vo[4], vf[4];
#pragma unroll
    for (int q = 0; q < 4; ++q) vo[q] = op[tid * 4 + q];
#pragma unroll
    for (int q = 0; q < 4; ++q) vf[q] = fp[tid * 4 + q];
#pragma unroll
    for (int q = 0; q < 4; ++q) {
      yo[4*q+0] = fabsf(vo[q].x); yo[4*q+1] = fabsf(vo[q].y);
      yo[4*q+2] = fabsf(vo[q].z); yo[4*q+3] = fabsf(vo[q].w);
      yf[4*q+0] = fabsf(vf[q].x); yf[4*q+1] = fabsf(vf[q].y);
      yf[4*q+2] = fabsf(vf[q].z); yf[4*q+3] = fabsf(vf[q].w);
    }
  }

  // ---- fused block scan of per-thread sums (obs & f together) ----
  float so = 0.f, sf = 0.f;
#pragma unroll
  for (int j = 0; j < EPT; ++j) { so += yo[j]; sf += yf[j]; }
  float vo = so, vf = sf;
#pragma unroll
  for (int off = 1; off < 64; off <<= 1) {
    float no = __shfl_up(vo, off, 64);
    float nf = __shfl_up(vf, off, 64);
    if (lane >= off) { vo += no; vf += nf; }
  }
  if (lane == 63) { sWo[wid] = vo; sWf[wid] = vf; }
  if (tid == 0)       { sY0o = yo[0];       sY0f = yf[0]; }
  if (tid == BLK - 1) { sYlo = yo[EPT - 1]; sYlf = yf[EPT - 1]; }
  __syncthreads();
  if (tid == 0) {
    float a = 0.f, b = 0.f;
#pragma unroll
    for (int w = 0; w < 4; ++w) {
      sWoOff[w] = a; a += sWo[w];
      sWfOff[w] = b; b += sWf[w];
    }
    sTotO = a; sTotF = b;
  }
  __syncthreads();

  const float exO  = (vo - so) + sWoOff[wid];
  const float exF  = (vf - sf) + sWfOff[wid];
  const float y0o  = sY0o;
  const float TrO  = sTotO - 0.5f * (sY0o + sYlo);
  const float invTO = 1.0f / TrO;

  // F at this thread's LAST element (closed form, no array needed)
  sFlast[tid] = (exO + so - yo[EPT-1] + 0.5f * (yo[EPT-1] - y0o)) * invTO;
  __syncthreads();

  // ---- per-thread interval ownership: write Q[k] for p_k in (F_prev, F_cur] ----
  {
    float aPrev = (tid == 0) ? 0.0f : sFlast[tid - 1];
    float ex = exO;
    int base = tid * EPT;
#pragma unroll
    for (int j = 0; j < EPT; ++j) {
      int k0 = base + j;
      float b = (ex + 0.5f * (yo[j] - y0o)) * invTO;
      ex += yo[j];
      if (k0 == 0) {
        sQ[0] = 0.0f;  // F_0 == 0 exactly; p_0 = 0 -> t_0
      } else {
        float a = aPrev;
        int kLo = (int)floorf(a * 99.0f);
        if (kLo < 0) kLo = 0;
        while (kLo > 0 && pgrid(kLo - 1) > a) --kLo;
        while (kLo <= 99 && pgrid(kLo) <= a) ++kLo;
        int kHi = (int)floorf(b * 99.0f) + 1;
        if (kHi > 99) kHi = 99;
        while (kHi >= 0 && pgrid(kHi) > b) --kHi;
        if (k0 == NT - 1) kHi = 99;  // np.interp: x beyond xp[-1] -> clamp/extrapolate tail
        float tPrev = (float)(k0 - 1) * DTIME;
        float denom = b - a;
        for (int k = kLo; k <= kHi; ++k) {
          float r = (denom > 0.f) ? (pgrid(k) - a) / denom : 1.0f;
          sQ[k] = tPrev + r * DTIME;
        }
      }
      aPrev = b;
    }
  }
  __syncthreads();

  // ---- PCR init: tridiag(1,4,1) * M_int = 6*(Q[i+2]-2Q[i+1]+Q[i])/h^2 ----
  int pp = 0;
  if (tid < NM) {
    float rhs = 6.0f * 99.0f * 99.0f * (sQ[tid + 2] - 2.0f * sQ[tid + 1] + sQ[tid]);
    sPa[0][tid] = (tid == 0)      ? 0.f : 1.f;
    sPb[0][tid] = 4.f;
    sPc[0][tid] = (tid == NM - 1) ? 0.f : 1.f;
    sPd[0][tid] = rhs;
  }
  __syncthreads();

  // ---- 7-step parallel cyclic reduction ----
  for (int s = 1; s < NM; s <<= 1) {
    if (tid < NM) {
      float ai = sPa[pp][tid], bi = sPb[pp][tid];
      float ci = sPc[pp][tid], di = sPd[pp][tid];
      float alpha = 0.f, am = 0.f, cm = 0.f, dm = 0.f;
      int im = tid - s;
      if (im >= 0) {
        float bm = sPb[pp][im];
        am = sPa[pp][im]; cm = sPc[pp][im]; dm = sPd[pp][im];
        alpha = -ai / bm;
      }
      float gamma = 0.f, ap = 0.f, cp2 = 0.f, dp2 = 0.f;
      int ip = tid + s;
      if (ip < NM) {
        float bp = sPb[pp][ip];
        ap = sPa[pp][ip]; cp2 = sPc[pp][ip]; dp2 = sPd[pp][ip];
        gamma = -ci / bp;
      }
      sPa[1 - pp][tid] = alpha * am;
      sPc[1 - pp][tid] = gamma * cp2;
      sPb[1 - pp][tid] = bi + alpha * cm + gamma * ap;
      sPd[1 - pp][tid] = di + alpha * dm + gamma * dp2;
    }
    pp ^= 1;
    __syncthreads();
  }

  if (tid < NM) sM[tid + 1] = sPd[pp][tid] / sPb[pp][tid];
  if (tid == NM) { sM[0] = 0.f; sM[NPP - 1] = 0.f; }
  __syncthreads();

  // ---- spline coefficients, float4-packed ----
  if (tid < NPP - 1) {
    float yi = sQ[tid], yi1 = sQ[tid + 1];
    float Mi = sM[tid], Mi1 = sM[tid + 1];
    float4 co;
    co.x = yi;
    co.y = (yi1 - yi) * 99.0f - (1.0f / 99.0f) * (2.0f * Mi + Mi1) * (1.0f / 6.0f);
    co.z = 0.5f * Mi;
    co.w = (Mi1 - Mi) * (99.0f / 6.0f);
    sCo[tid] = co;
  }
  __syncthreads();

  // ---- Phase B: evaluate on f's CDF, accumulate weighted squared diff ----
  const float y0f  = sY0f;
  const float TrF  = sTotF - 0.5f * (sY0f + sYlf);
  const float invTF = 1.0f / TrF;
  float acc = 0.f;
  {
    float ex = exF;
    int base = tid * EPT;
#pragma unroll
    for (int j = 0; j < EPT; ++j) {
      int k = base + j;
      float yv = yf[j];
      float Fk = (ex + 0.5f * (yv - y0f)) * invTF;
      ex += yv;
      float xi = fminf(fmaxf(Fk, 0.f), 1.f);
      int idx = (int)(xi * 99.0f);
      if (idx > NPP - 2) idx = NPP - 2;
      float dxv = xi - (float)idx * (1.0f / 99.0f);
      float4 co = sCo[idx];
      float val = co.x + dxv * (co.y + dxv * (co.z + dxv * co.w));
      float tk = (float)k * DTIME;
      float diff = tk - val;
      float w = (k == 0 || k == NT - 1) ? 0.5f : 1.0f;
      acc += w * diff * diff * yv;
    }
  }

  // ---- block reduce ----
#pragma unroll
  for (int off = 32; off > 0; off >>= 1) acc += __shfl_down(acc, off, 64);
  if (lane == 0) sWo[wid] = acc;
  __syncthreads();
  if (tid == 0) {
    rowOut[row] = (sWo[0] + sWo[1] + sWo[2] + sWo[3]) * invTF;
  }
}

// Deterministic final reduce: 2048 floats -> 1, double accumulation.
__global__ __launch_bounds__(256) void wass_reduce_kernel(
    const float* __restrict__ rowOut, float* __restrict__ out) {
  __shared__ double sW[4];
  int tid = threadIdx.x;
  int lane = tid & 63, wid = tid >> 6;
  double acc = 0.0;
  for (int i = tid; i < NROWS; i += 256) acc += (double)rowOut[i];
#pragma unroll
  for (int off = 32; off > 0; off >>= 1) acc += __shfl_down(acc, off, 64);
  if (lane == 0) sW[wid] = acc;
  __syncthreads();
  if (tid == 0) out[0] = (float)(sW[0] + sW[1] + sW[2] + sW[3]);
}

extern "C" void kernel_launch(void* const* d_in, const int* in_sizes, int n_in,
                              void* d_out, int out_size, void* d_ws, size_t ws_size,
                              hipStream_t stream) {
  (void)in_sizes; (void)n_in; (void)out_size; (void)ws_size;
  const float* f   = (const float*)d_in[0];
  const float* obs = (const float*)d_in[1];
  // d_in[2] (t) is analytic: t[k] = k * 0.001f — computed inline.
  float* rowOut = (float*)d_ws;  // NROWS floats

  wass_row_kernel<<<NROWS, BLK, 0, stream>>>(f, obs, rowOut);
  wass_reduce_kernel<<<1, 256, 0, stream>>>(rowOut, (float*)d_out);
}

// Round 3
// 99.952 us; speedup vs baseline: 1.4104x; 1.4104x over previous
//
#include <hip/hip_runtime.h>

#define NT 4096
#define NPP 100
#define NROWS 2048
#define BLK 256
#define EPT 16           // 256*16 = 4096
#define NM 98            // interior spline unknowns
#define DTIME 0.001f
#define HF (1.0f / 99.0f)

// Inverse kernel of tridiag(1,4,1): G(d) = r^|d| / (2*sqrt(3)), r = sqrt(3)-2.
// Truncated at |d|=12 (rel err ~4e-8). Sum over all d = 1/6 (sanity-checked).
__device__ __constant__ float GW[13] = {
    0.288675135f,    -0.077350269f,   0.020725943f,   -0.0055534374f,
    0.0014880647f,   -0.00039874667f, 0.00010684152f, -2.8626968e-05f,
    7.6707195e-06f,  -2.0554928e-06f, 5.5072549e-07f, -1.4756630e-07f,
    3.9539424e-08f};

// swizzled CDF index: pad 1 dword per 16 -> lane stride 17 (odd) = conflict-free
__device__ __forceinline__ int swz(int k) { return k + (k >> 4); }

__global__ __launch_bounds__(BLK) void wass_row_kernel(
    const float* __restrict__ f, const float* __restrict__ obs,
    float* __restrict__ rowOut) {
  const int row  = blockIdx.x;
  const int tid  = threadIdx.x;
  const int lane = tid & 63;
  const int wid  = tid >> 6;

  __shared__ float sF[NT + NT / 16];  // swizzled obs CDF; overlaid after search
  __shared__ float sQ[NPP];
  __shared__ float sWo[4], sWf[4], sWoOff[4], sWfOff[4];
  __shared__ float sTotO, sTotF, sY0o, sYlo, sY0f, sYlf;
  // overlays into sF (dead after the search):
  float* sRhs = sF;                    // [0..97]
  float* sM   = sF + 128;              // [0..99]
  float4* sCo = (float4*)(sF + 256);   // [0..98], 16B-aligned (256 floats=1KB)

  // ---- issue BOTH rows' loads up front ----
  float yo[EPT], yf[EPT];
  {
    const float4* op = (const float4*)(obs + (size_t)row * NT);
    const float4* fp = (const float4*)(f + (size_t)row * NT);
    float4 vo[4], vf[4];
#pragma unroll
    for (int q = 0; q < 4; ++q) vo[q] = op[tid * 4 + q];
#pragma unroll
    for (int q = 0; q < 4; ++q) vf[q] = fp[tid * 4 + q];
#pragma unroll
    for (int q = 0; q < 4; ++q) {
      yo[4*q+0] = fabsf(vo[q].x); yo[4*q+1] = fabsf(vo[q].y);
      yo[4*q+2] = fabsf(vo[q].z); yo[4*q+3] = fabsf(vo[q].w);
      yf[4*q+0] = fabsf(vf[q].x); yf[4*q+1] = fabsf(vf[q].y);
      yf[4*q+2] = fabsf(vf[q].z); yf[4*q+3] = fabsf(vf[q].w);
    }
  }

  // ---- fused block scan of per-thread sums ----
  float so = 0.f, sf = 0.f;
#pragma unroll
  for (int j = 0; j < EPT; ++j) { so += yo[j]; sf += yf[j]; }
  float vo = so, vf = sf;
#pragma unroll
  for (int off = 1; off < 64; off <<= 1) {
    float no = __shfl_up(vo, off, 64);
    float nf = __shfl_up(vf, off, 64);
    if (lane >= off) { vo += no; vf += nf; }
  }
  if (lane == 63) { sWo[wid] = vo; sWf[wid] = vf; }
  if (tid == 0)       { sY0o = yo[0];       sY0f = yf[0]; }
  if (tid == BLK - 1) { sYlo = yo[EPT - 1]; sYlf = yf[EPT - 1]; }
  __syncthreads();
  if (tid == 0) {
    float a = 0.f, b = 0.f;
#pragma unroll
    for (int w = 0; w < 4; ++w) {
      sWoOff[w] = a; a += sWo[w];
      sWfOff[w] = b; b += sWf[w];
    }
    sTotO = a; sTotF = b;
  }
  __syncthreads();

  const float exO0 = (vo - so) + sWoOff[wid];
  const float exF0 = (vf - sf) + sWfOff[wid];
  const float y0f  = sY0f;
  const float TrF  = sTotF - 0.5f * (sY0f + sYlf);
  const float invTF = 1.0f / TrF;

  // ---- obs CDF -> swizzled LDS (regular, conflict-free) ----
  {
    const float invT = 1.0f / (sTotO - 0.5f * (sY0o + sYlo));
    const float hInv = 0.5f * invT;
    const float c0   = sY0o * hInv;
    float ex = exO0;
    int b17 = tid * 17;
#pragma unroll
    for (int j = 0; j < EPT; ++j) {
      sF[b17 + j] = fmaf(ex, invT, fmaf(yo[j], hInv, -c0));
      ex += yo[j];
    }
  }
  __syncthreads();

  // ---- inverse CDF via binary search (100 threads, 12 regular probes) ----
  if (tid < NPP) {
    float x = (float)((double)tid * (1.0 / 99.0));
    int lo = 0, hi = NT;
#pragma unroll
    for (int it = 0; it < 12; ++it) {
      int mid = (lo + hi) >> 1;
      float v = sF[swz(mid)];
      if (v > x) hi = mid; else lo = mid + 1;
    }
    int i = lo;
    if (i < 1) i = 1;
    if (i > NT - 1) i = NT - 1;
    float Fj = sF[swz(i - 1)], Fi = sF[swz(i)];
    float dxv = Fi - Fj;
    float tj = (float)(i - 1) * DTIME;
    float qv = (dxv == 0.0f) ? (float)i * DTIME
                             : fmaf((x - Fj) / dxv, DTIME, tj);
    sQ[tid] = qv;
  }
  __syncthreads();  // sF dead; overlays live from here

  // ---- rhs of tridiag system ----
  if (tid < NM) {
    sRhs[tid] = (6.0f * 99.0f * 99.0f) *
                (sQ[tid + 2] - 2.0f * sQ[tid + 1] + sQ[tid]);
  }
  __syncthreads();

  // ---- tridiag(1,4,1) solve = 25-tap constant convolution + odd images ----
  if (tid < NM) {
    float m = 0.f;
#pragma unroll
    for (int d = -12; d <= 12; ++d) {
      int j = tid + d;
      bool neg = (j < 0), pos = (j > NM - 1);
      int jr = neg ? (-2 - j) : (pos ? (2 * NM - j) : j);
      jr = jr < 0 ? 0 : (jr > NM - 1 ? NM - 1 : jr);
      bool z = (j == -1) || (j == NM);
      float v = sRhs[jr];
      v = (neg || pos) ? -v : v;
      v = z ? 0.f : v;
      m = fmaf(GW[d < 0 ? -d : d], v, m);
    }
    sM[tid + 1] = m;
  }
  if (tid == NM) { sM[0] = 0.f; sM[NPP - 1] = 0.f; }
  __syncthreads();

  // ---- spline coefficients (float4-packed) ----
  if (tid < NPP - 1) {
    float yi = sQ[tid], yi1 = sQ[tid + 1];
    float Mi = sM[tid], Mi1 = sM[tid + 1];
    float4 co;
    co.x = yi;
    co.y = (yi1 - yi) * 99.0f - HF * (2.0f * Mi + Mi1) * (1.0f / 6.0f);
    co.z = 0.5f * Mi;
    co.w = (Mi1 - Mi) * (99.0f / 6.0f);
    sCo[tid] = co;
  }
  __syncthreads();

  // ---- Phase B: f CDF -> spline eval -> weighted accumulation ----
  float acc = 0.f;
  {
    const float hInv = 0.5f * invTF;
    const float c0   = y0f * hInv;
    float ex = exF0;
    const float tBase = (float)(tid * EPT) * DTIME;
#pragma unroll
    for (int j = 0; j < EPT; ++j) {
      int k = tid * EPT + j;
      float yv = yf[j];
      float Fk = fmaf(ex, invTF, fmaf(yv, hInv, -c0));
      ex += yv;
      float xi = fminf(fmaxf(Fk, 0.f), 1.f);
      int idx = (int)(xi * 99.0f);
      if (idx > NPP - 2) idx = NPP - 2;
      float dxv = fmaf(-(float)idx, HF, xi);
      float4 co = sCo[idx];
      float val = fmaf(dxv, fmaf(dxv, fmaf(dxv, co.w, co.z), co.y), co.x);
      float tk = fmaf((float)j, DTIME, tBase);
      float diff = tk - val;
      float w = (k == 0 || k == NT - 1) ? 0.5f : 1.0f;
      acc = fmaf(w * diff, diff * yv, acc);
    }
  }

  // ---- block reduce ----
#pragma unroll
  for (int off = 32; off > 0; off >>= 1) acc += __shfl_down(acc, off, 64);
  if (lane == 0) sWo[wid] = acc;
  __syncthreads();
  if (tid == 0) {
    rowOut[row] = (sWo[0] + sWo[1] + sWo[2] + sWo[3]) * invTF;
  }
}

// Deterministic final reduce: 2048 floats -> 1, double accumulation.
__global__ __launch_bounds__(256) void wass_reduce_kernel(
    const float* __restrict__ rowOut, float* __restrict__ out) {
  __shared__ double sW[4];
  int tid = threadIdx.x;
  int lane = tid & 63, wid = tid >> 6;
  double acc = 0.0;
  for (int i = tid; i < NROWS; i += 256) acc += (double)rowOut[i];
#pragma unroll
  for (int off = 32; off > 0; off >>= 1) acc += __shfl_down(acc, off, 64);
  if (lane == 0) sW[wid] = acc;
  __syncthreads();
  if (tid == 0) out[0] = (float)(sW[0] + sW[1] + sW[2] + sW[3]);
}

extern "C" void kernel_launch(void* const* d_in, const int* in_sizes, int n_in,
                              void* d_out, int out_size, void* d_ws, size_t ws_size,
                              hipStream_t stream) {
  (void)in_sizes; (void)n_in; (void)out_size; (void)ws_size;
  const float* f   = (const float*)d_in[0];
  const float* obs = (const float*)d_in[1];
  // d_in[2] (t) is analytic: t[k] = k * 0.001f — computed inline.
  float* rowOut = (float*)d_ws;  // NROWS floats

  wass_row_kernel<<<NROWS, BLK, 0, stream>>>(f, obs, rowOut);
  wass_reduce_kernel<<<1, 256, 0, stream>>>(rowOut, (float*)d_out);
}